// Round 17
// baseline (508.820 us; speedup 1.0000x reference)
//
#include <hip/hip_runtime.h>
#include <hip/hip_fp16.h>

#define TT 100
#define BB 4096
#define GS 488   // floats per batch blob; 2 blobs/wave (dual-batch)

// R17: DUAL-BATCH WAVE. Each 64-lane wave processes TWO batches (A,B) with
// R16's exact per-batch logic. CDNA waves issue in-order, so 4-way TLP left
// 45% of VALU slots empty (R16: 55% busy); two independent A/B chains in one
// basic block let the COMPILER statically interleave -> fills dependency
// stalls. One FENCE covers both batches (fence/batch halved).
// Lane layout per batch: lane = 4*l + qd; l=column, qd owns Q rows [4qd,4qd+4).

#define FENCE() asm volatile("s_waitcnt lgkmcnt(0)" ::: "memory")

__device__ __forceinline__ float frcp(float x){ return __builtin_amdgcn_rcpf(x); }

template<int CTRL>
__device__ __forceinline__ float qbcast(float x){
  return __int_as_float(__builtin_amdgcn_update_dpp(0, __float_as_int(x), CTRL, 0xF, 0xF, true));
}
__device__ __forceinline__ float quadsum(float x){
  int a = __builtin_amdgcn_update_dpp(0, __float_as_int(x), 0xB1, 0xF, 0xF, true);
  x += __int_as_float(a);
  int c = __builtin_amdgcn_update_dpp(0, __float_as_int(x), 0x4E, 0xF, 0xF, true);
  x += __int_as_float(c);
  return x;
}
__device__ __forceinline__ float readlanef(float x, int srclane){
  return __int_as_float(__builtin_amdgcn_readlane(__float_as_int(x), srclane));
}
template<int CTRL>
__device__ __forceinline__ float ror_add(float x){
  int r = __builtin_amdgcn_update_dpp(0, __float_as_int(x), CTRL, 0xF, 0xF, true);
  return x + __int_as_float(r);
}
__device__ __forceinline__ float reduce16_dpp(float x){
  x = ror_add<0x128>(x); x = ror_add<0x124>(x);
  x = ror_add<0x122>(x); x = ror_add<0x121>(x);
  return x;
}

template<int KMODE>
__device__ __forceinline__ void storeK(void* wsb_, int l, float X0,float X1,float X2,float X3){
  if (KMODE==0){
    float* wsb=(float*)wsb_;
    if (l<12)       ((float4*)wsb)[l]  = make_float4(X0,X1,X2,X3);
    else if (l==12) ((float4*)wsb)[12] = make_float4(X0,X1,X2,X3);
  } else {
    __half* wsb=(__half*)wsb_;
    if (l<12){
      wsb[l*4+0]=__float2half(X0); wsb[l*4+1]=__float2half(X1);
      wsb[l*4+2]=__float2half(X2); wsb[l*4+3]=__float2half(X3);
    } else if (l==12){
      wsb[48]=__float2half(X0); wsb[49]=__float2half(X1);
      wsb[50]=__float2half(X2); wsb[51]=__float2half(X3);
    }
  }
}
template<int KMODE>
__device__ __forceinline__ float4 loadKcol(const void* wsb_, int l){
  if (KMODE==0) return ((const float4*)wsb_)[l];
  const __half* p=(const __half*)wsb_ + l*4;
  return make_float4(__half2float(p[0]),__half2float(p[1]),__half2float(p[2]),__half2float(p[3]));
}
template<int KMODE>
__device__ __forceinline__ float loadkk(const void* wsb_, int r){
  if (KMODE==0) return ((const float*)wsb_)[48+r];
  return __half2float(((const __half*)wsb_)[48+r]);
}

// W-triplet for one batch: W[j] = V[s0+j][:] . Ftj[:]
__device__ __forceinline__ void wtrip(const float* Vb, const float* Ftj, int s0,
                                      float& W0, float& W1, float& W2){
  const float4* vr0=(const float4*)(Vb+(s0+0)*12);
  const float4* vr1=(const float4*)(Vb+(s0+1)*12);
  const float4* vr2=(const float4*)(Vb+(s0+2)*12);
  float4 a0=vr0[0],a1=vr0[1],a2=vr0[2];
  W0 = a0.x*Ftj[0]+a0.y*Ftj[1]+a0.z*Ftj[2]+a0.w*Ftj[3]
     + a1.x*Ftj[4]+a1.y*Ftj[5]+a1.z*Ftj[6]+a1.w*Ftj[7]
     + a2.x*Ftj[8]+a2.y*Ftj[9]+a2.z*Ftj[10]+a2.w*Ftj[11];
  float4 b0=vr1[0],b1=vr1[1],b2=vr1[2];
  W1 = b0.x*Ftj[0]+b0.y*Ftj[1]+b0.z*Ftj[2]+b0.w*Ftj[3]
     + b1.x*Ftj[4]+b1.y*Ftj[5]+b1.z*Ftj[6]+b1.w*Ftj[7]
     + b2.x*Ftj[8]+b2.y*Ftj[9]+b2.z*Ftj[10]+b2.w*Ftj[11];
  float4 c0=vr2[0],c1=vr2[1],c2=vr2[2];
  W2 = c0.x*Ftj[0]+c0.y*Ftj[1]+c0.z*Ftj[2]+c0.w*Ftj[3]
     + c1.x*Ftj[4]+c1.y*Ftj[5]+c1.z*Ftj[6]+c1.w*Ftj[7]
     + c2.x*Ftj[8]+c2.y*Ftj[9]+c2.z*Ftj[10]+c2.w*Ftj[11];
}

template<int KMODE>
__global__ __launch_bounds__(64)
void lqr_fused(const float* __restrict__ xinit,
               const float* __restrict__ Cg,
               const float* __restrict__ cg,
               const float* __restrict__ Fg,
               const float* __restrict__ fg,
               float* __restrict__ out,
               void* __restrict__ wsv)
{
  __shared__ float smem[GS*2];
  const int lane = threadIdx.x & 63;
  const int bA   = blockIdx.x*2;
  const int bB   = bA + 1;
  const int l    = lane >> 2;
  const int qd   = lane & 3;
  const int KSZ  = (KMODE==0?4:2);

  float* __restrict__ VbA = smem;        float* __restrict__ VbB = smem + GS;
  float* __restrict__ FlA = VbA + 144;   float* __restrict__ FlB = VbB + 144;
  float* __restrict__ vvA = VbA + 384;   float* __restrict__ vvB = VbB + 384;
  float* __restrict__ tbA = VbA + 396;   float* __restrict__ tbB = VbB + 396;

  if (l<12){
    if (qd<3){
      *(float4*)(VbA + l*12 + 4*qd) = make_float4(0,0,0,0);
      *(float4*)(VbB + l*12 + 4*qd) = make_float4(0,0,0,0);
    } else { vvA[l]=0.f; vvB[l]=0.f; }
  }

  // ================= backward Riccati (dual) =================
  const size_t ofA = ((size_t)(TT-1)*BB + bA);
  const float* pCA = Cg + ofA*256 + l*16 + 4*qd;  const float* pCB = pCA + 256;
  const float* pcA = cg + ofA*16 + l;             const float* pcB = pcA + 16;
  const float* pFA = Fg + ofA*192 + lane*4;       const float* pFB = pFA + 192;
  const float* pfA = fg + ofA*12 + l;             const float* pfB = pfA + 12;
  char*        pWA = (char*)wsv + ofA*52*KSZ;     char*        pWB = pWA + 52*KSZ;

  float4 sCqA=*(const float4*)pCA, sCqB=*(const float4*)pCB;
  float  scA_=*pcA, scB_=*pcB;
  float4 sFstA=make_float4(0,0,0,0), sFstB=sFstA;
  float  sftvA=0.f, sftvB=0.f;

  for (int tt=TT-1; tt>=0; --tt){
    const bool hasF = (tt < TT-1);
    const float4 CqA=sCqA, CqB=sCqB; const float rcA=scA_, rcB=scB_;
    const float4 FstA=sFstA, FstB=sFstB; const float ftvA=sftvA, ftvB=sftvB;

    if (hasF){
      if (lane<48){
        *(float4*)(FlA + l*20 + 4*qd) = FstA;
        *(float4*)(FlB + l*20 + 4*qd) = FstB;
      }
      if (qd==0 && l<12){ tbA[l]=ftvA; tbB[l]=ftvB; }
    }
    FENCE(); // one fence covers BOTH batches' staging + prev V/vv

    if (tt>0){
      pCA -= (size_t)BB*256; pCB -= (size_t)BB*256;
      pcA -= (size_t)BB*16;  pcB -= (size_t)BB*16;
      sCqA = *(const float4*)pCA; sCqB = *(const float4*)pCB;
      scA_ = *pcA;                scB_ = *pcB;
      if (lane<48){
        pFA -= (size_t)BB*192; pFB -= (size_t)BB*192;
        sFstA = *(const float4*)pFA; sFstB = *(const float4*)pFB;
      }
      if (qd==0 && l<12){
        pfA -= (size_t)BB*12; pfB -= (size_t)BB*12;
        sftvA = *pfA; sftvB = *pfB;
      }
    }

    float QrA0=CqA.x, QrA1=CqA.y, QrA2=CqA.z, QrA3=CqA.w;
    float QrB0=CqB.x, QrB1=CqB.y, QrB2=CqB.z, QrB3=CqB.w;
    float qfA=0.f, qfB=0.f;

    if (hasF){
      float FtjA[12], FtjB[12];
      #pragma unroll
      for (int t=0;t<12;t++){ FtjA[t]=FlA[t*20+l]; FtjB[t]=FlB[t*20+l]; }
      const int s0=3*qd;
      float WA0,WA1,WA2, WB0,WB1,WB2;
      wtrip(VbA, FtjA, s0, WA0,WA1,WA2);
      wtrip(VbB, FtjB, s0, WB0,WB1,WB2);

      float WfA[12], WfB[12];
      WfA[0]=qbcast<0x00>(WA0); WfA[1]=qbcast<0x00>(WA1); WfA[2]=qbcast<0x00>(WA2);
      WfA[3]=qbcast<0x55>(WA0); WfA[4]=qbcast<0x55>(WA1); WfA[5]=qbcast<0x55>(WA2);
      WfA[6]=qbcast<0xAA>(WA0); WfA[7]=qbcast<0xAA>(WA1); WfA[8]=qbcast<0xAA>(WA2);
      WfA[9]=qbcast<0xFF>(WA0); WfA[10]=qbcast<0xFF>(WA1); WfA[11]=qbcast<0xFF>(WA2);
      WfB[0]=qbcast<0x00>(WB0); WfB[1]=qbcast<0x00>(WB1); WfB[2]=qbcast<0x00>(WB2);
      WfB[3]=qbcast<0x55>(WB0); WfB[4]=qbcast<0x55>(WB1); WfB[5]=qbcast<0x55>(WB2);
      WfB[6]=qbcast<0xAA>(WB0); WfB[7]=qbcast<0xAA>(WB1); WfB[8]=qbcast<0xAA>(WB2);
      WfB[9]=qbcast<0xFF>(WB0); WfB[10]=qbcast<0xFF>(WB1); WfB[11]=qbcast<0xFF>(WB2);

      #pragma unroll
      for (int s=0;s<12;s++){
        const float4 f4A = *(const float4*)(FlA + s*20 + 4*qd);
        const float4 f4B = *(const float4*)(FlB + s*20 + 4*qd);
        QrA0 += f4A.x*WfA[s]; QrA1 += f4A.y*WfA[s];
        QrA2 += f4A.z*WfA[s]; QrA3 += f4A.w*WfA[s];
        QrB0 += f4B.x*WfB[s]; QrB1 += f4B.y*WfB[s];
        QrB2 += f4B.z*WfB[s]; QrB3 += f4B.w*WfB[s];
      }
      qfA = WA0*tbA[s0] + WA1*tbA[s0+1] + WA2*tbA[s0+2];
      qfB = WB0*tbB[s0] + WB1*tbB[s0+1] + WB2*tbB[s0+2];
      const float ftaA = qd==0?FtjA[0]:qd==1?FtjA[3]:qd==2?FtjA[6]:FtjA[9];
      const float ftbA = qd==0?FtjA[1]:qd==1?FtjA[4]:qd==2?FtjA[7]:FtjA[10];
      const float ftcA = qd==0?FtjA[2]:qd==1?FtjA[5]:qd==2?FtjA[8]:FtjA[11];
      qfA += ftaA*vvA[s0] + ftbA*vvA[s0+1] + ftcA*vvA[s0+2];
      const float ftaB = qd==0?FtjB[0]:qd==1?FtjB[3]:qd==2?FtjB[6]:FtjB[9];
      const float ftbB = qd==0?FtjB[1]:qd==1?FtjB[4]:qd==2?FtjB[7]:FtjB[10];
      const float ftcB = qd==0?FtjB[2]:qd==1?FtjB[5]:qd==2?FtjB[8]:FtjB[11];
      qfB += ftaB*vvB[s0] + ftbB*vvB[s0+1] + ftcB*vvB[s0+2];
    }
    const float qvA = rcA + quadsum(qfA);
    const float qvB = rcB + quadsum(qfB);

    // ---- batch A: Quu/qu, LU, K/k ----
    float aA00=readlanef(QrA0,51),aA01=readlanef(QrA0,55),aA02=readlanef(QrA0,59),aA03=readlanef(QrA0,63);
    float aA10=readlanef(QrA1,51),aA11=readlanef(QrA1,55),aA12=readlanef(QrA1,59),aA13=readlanef(QrA1,63);
    float aA20=readlanef(QrA2,51),aA21=readlanef(QrA2,55),aA22=readlanef(QrA2,59),aA23=readlanef(QrA2,63);
    float aA30=readlanef(QrA3,51),aA31=readlanef(QrA3,55),aA32=readlanef(QrA3,59),aA33=readlanef(QrA3,63);
    const float quA0=readlanef(qvA,48),quA1=readlanef(qvA,52),quA2=readlanef(qvA,56),quA3=readlanef(qvA,60);
    // ---- batch B ----
    float aB00=readlanef(QrB0,51),aB01=readlanef(QrB0,55),aB02=readlanef(QrB0,59),aB03=readlanef(QrB0,63);
    float aB10=readlanef(QrB1,51),aB11=readlanef(QrB1,55),aB12=readlanef(QrB1,59),aB13=readlanef(QrB1,63);
    float aB20=readlanef(QrB2,51),aB21=readlanef(QrB2,55),aB22=readlanef(QrB2,59),aB23=readlanef(QrB2,63);
    float aB30=readlanef(QrB3,51),aB31=readlanef(QrB3,55),aB32=readlanef(QrB3,59),aB33=readlanef(QrB3,63);
    const float quB0=readlanef(qvB,48),quB1=readlanef(qvB,52),quB2=readlanef(qvB,56),quB3=readlanef(qvB,60);

    const float bA0=-qbcast<0xFF>(QrA0), bA1=-qbcast<0xFF>(QrA1),
                bA2=-qbcast<0xFF>(QrA2), bA3=-qbcast<0xFF>(QrA3);
    const float bB0=-qbcast<0xFF>(QrB0), bB1=-qbcast<0xFF>(QrB1),
                bB2=-qbcast<0xFF>(QrB2), bB3=-qbcast<0xFF>(QrB3);
    float bbA0=bA0,bbA1=bA1,bbA2=bA2,bbA3=bA3;
    float bbB0=bB0,bbB1=bB1,bbB2=bB2,bbB3=bB3;

    // LU A
    const float iA0=frcp(aA00);
    const float mA10=aA10*iA0,mA20=aA20*iA0,mA30=aA30*iA0;
    aA11-=mA10*aA01;aA12-=mA10*aA02;aA13-=mA10*aA03;
    aA21-=mA20*aA01;aA22-=mA20*aA02;aA23-=mA20*aA03;
    aA31-=mA30*aA01;aA32-=mA30*aA02;aA33-=mA30*aA03;
    bbA1-=mA10*bbA0;bbA2-=mA20*bbA0;bbA3-=mA30*bbA0;
    const float iA1=frcp(aA11);
    const float mA21=aA21*iA1,mA31=aA31*iA1;
    aA22-=mA21*aA12;aA23-=mA21*aA13;
    aA32-=mA31*aA12;aA33-=mA31*aA13;
    bbA2-=mA21*bbA1;bbA3-=mA31*bbA1;
    const float iA2=frcp(aA22);
    const float mA32=aA32*iA2;
    aA33-=mA32*aA23;
    bbA3-=mA32*bbA2;
    const float iA3=frcp(aA33);
    const float XA3=bbA3*iA3;
    const float XA2=(bbA2-aA23*XA3)*iA2;
    const float XA1=(bbA1-aA12*XA2-aA13*XA3)*iA1;
    const float XA0=(bbA0-aA01*XA1-aA02*XA2-aA03*XA3)*iA0;
    float cA0=-quA0,cA1=-quA1,cA2=-quA2,cA3=-quA3;
    cA1-=mA10*cA0;cA2-=mA20*cA0;cA3-=mA30*cA0;
    cA2-=mA21*cA1;cA3-=mA31*cA1;
    cA3-=mA32*cA2;
    const float kA3=cA3*iA3;
    const float kA2=(cA2-aA23*kA3)*iA2;
    const float kA1=(cA1-aA12*kA2-aA13*kA3)*iA1;
    const float kA0=(cA0-aA01*kA1-aA02*kA2-aA03*kA3)*iA0;
    // LU B
    const float iB0=frcp(aB00);
    const float mB10=aB10*iB0,mB20=aB20*iB0,mB30=aB30*iB0;
    aB11-=mB10*aB01;aB12-=mB10*aB02;aB13-=mB10*aB03;
    aB21-=mB20*aB01;aB22-=mB20*aB02;aB23-=mB20*aB03;
    aB31-=mB30*aB01;aB32-=mB30*aB02;aB33-=mB30*aB03;
    bbB1-=mB10*bbB0;bbB2-=mB20*bbB0;bbB3-=mB30*bbB0;
    const float iB1=frcp(aB11);
    const float mB21=aB21*iB1,mB31=aB31*iB1;
    aB22-=mB21*aB12;aB23-=mB21*aB13;
    aB32-=mB31*aB12;aB33-=mB31*aB13;
    bbB2-=mB21*bbB1;bbB3-=mB31*bbB1;
    const float iB2=frcp(aB22);
    const float mB32=aB32*iB2;
    aB33-=mB32*aB23;
    bbB3-=mB32*bbB2;
    const float iB3=frcp(aB33);
    const float XB3=bbB3*iB3;
    const float XB2=(bbB2-aB23*XB3)*iB2;
    const float XB1=(bbB1-aB12*XB2-aB13*XB3)*iB1;
    const float XB0=(bbB0-aB01*XB1-aB02*XB2-aB03*XB3)*iB0;
    float cB0=-quB0,cB1=-quB1,cB2=-quB2,cB3=-quB3;
    cB1-=mB10*cB0;cB2-=mB20*cB0;cB3-=mB30*cB0;
    cB2-=mB21*cB1;cB3-=mB31*cB1;
    cB3-=mB32*cB2;
    const float kB3=cB3*iB3;
    const float kB2=(cB2-aB23*kB3)*iB2;
    const float kB1=(cB1-aB12*kB2-aB13*kB3)*iB1;
    const float kB0=(cB0-aB01*kB1-aB02*kB2-aB03*kB3)*iB0;

    if (qd==0){
      storeK<KMODE>(pWA, l, l<12?XA0:kA0, l<12?XA1:kA1, l<12?XA2:kA2, l<12?XA3:kA3);
      storeK<KMODE>(pWB, l, l<12?XB0:kB0, l<12?XB1:kB1, l<12?XB2:kB2, l<12?XB3:kB3);
    }
    pWA -= (size_t)BB*52*KSZ; pWB -= (size_t)BB*52*KSZ;

    float vnA0=QrA0, vnA1=QrA1, vnA2=QrA2, vnA3=QrA3;
    float vnB0=QrB0, vnB1=QrB1, vnB2=QrB2, vnB3=QrB3;
    #pragma unroll
    for (int r=0;r<4;r++){
      const float XrA = r==0?XA0:r==1?XA1:r==2?XA2:XA3;
      const float XrB = r==0?XB0:r==1?XB1:r==2?XB2:XB3;
      vnA0 += __shfl(QrA0, 48+4*r+qd, 64) * XrA;
      vnA1 += __shfl(QrA1, 48+4*r+qd, 64) * XrA;
      vnA2 += __shfl(QrA2, 48+4*r+qd, 64) * XrA;
      vnA3 += __shfl(QrA3, 48+4*r+qd, 64) * XrA;
      vnB0 += __shfl(QrB0, 48+4*r+qd, 64) * XrB;
      vnB1 += __shfl(QrB1, 48+4*r+qd, 64) * XrB;
      vnB2 += __shfl(QrB2, 48+4*r+qd, 64) * XrB;
      vnB3 += __shfl(QrB3, 48+4*r+qd, 64) * XrB;
    }
    if (l<12){
      if (qd<3){
        *(float4*)(VbA + l*12 + 4*qd) = make_float4(vnA0,vnA1,vnA2,vnA3);
        *(float4*)(VbB + l*12 + 4*qd) = make_float4(vnB0,vnB1,vnB2,vnB3);
      } else {
        vvA[l] = qvA + QrA0*kA0 + QrA1*kA1 + QrA2*kA2 + QrA3*kA3;
        vvB[l] = qvB + QrB0*kB0 + QrB1*kB1 + QrB2*kB2 + QrB3*kB3;
      }
    }
  }

  // drain K/k global stores before forward reads them
  asm volatile("s_waitcnt vmcnt(0)" ::: "memory");

  // ================= forward rollout (dual) =================
  const int fl = lane & 15;
  const int g4 = lane >> 4;

  float xjA = (g4==0 && fl<12)? xinit[(size_t)bA*12+fl] : 0.f;
  float xjB = (g4==0 && fl<12)? xinit[(size_t)bB*12+fl] : 0.f;
  double costA=0.0, costB=0.0;

  const float* qCA = Cg + (size_t)bA*256 + fl*16 + 4*g4;  const float* qCB = qCA + 256;
  const float* qcA = cg + (size_t)bA*16 + fl;             const float* qcB = qcA + 16;
  const float* qFA = Fg + (size_t)bA*192 + fl*16;         const float* qFB = qFA + 192;
  const float* qfA2= fg + (size_t)bA*12 + fl;             const float* qfB2= qfA2 + 12;
  const char*  qKA = (const char*)wsv + (size_t)bA*52*KSZ; const char* qKB = qKA + 52*KSZ;

  float4 sCaA, sCaB; float sc2A, sc2B;
  float4 sFA0=make_float4(0,0,0,0),sFA1=sFA0,sFA2=sFA0,sFA3=sFA0; float sfA_=0.f;
  float4 sFB0=sFA0,sFB1=sFA0,sFB2=sFA0,sFB3=sFA0;                 float sfB_=0.f;
  float4 sKA=make_float4(0,0,0,0), sKB=sKA; float skA_=0.f, skB_=0.f;
  {
    sCaA = *(const float4*)qCA;  sCaB = *(const float4*)qCB;
    sc2A = *qcA;                 sc2B = *qcB;
    if (g4==0 && fl<12){
      const float4* p4A=(const float4*)qFA; const float4* p4B=(const float4*)qFB;
      sFA0=p4A[0];sFA1=p4A[1];sFA2=p4A[2];sFA3=p4A[3];
      sFB0=p4B[0];sFB1=p4B[1];sFB2=p4B[2];sFB3=p4B[3];
      sfA_=*qfA2; sfB_=*qfB2;
      sKA=loadKcol<KMODE>(qKA,fl); sKB=loadKcol<KMODE>(qKB,fl);
    }
    if (g4==0 && fl>=12){ skA_=loadkk<KMODE>(qKA,fl-12); skB_=loadkk<KMODE>(qKB,fl-12); }
  }

  for (int t=0;t<TT;t++){
    float4 CaA=sCaA, CaB=sCaB; float rcA=sc2A, rcB=sc2B;
    float4 FA0=sFA0,FA1=sFA1,FA2=sFA2,FA3=sFA3; float rfA=sfA_;
    float4 FB0=sFB0,FB1=sFB1,FB2=sFB2,FB3=sFB3; float rfB=sfB_;
    float4 KA4=sKA, KB4=sKB; float klA=skA_, klB=skB_;

    if (t+1<TT){
      qCA += (size_t)BB*256; qCB += (size_t)BB*256;
      qcA += (size_t)BB*16;  qcB += (size_t)BB*16;
      qKA += (size_t)BB*52*KSZ; qKB += (size_t)BB*52*KSZ;
      sCaA = *(const float4*)qCA; sCaB = *(const float4*)qCB;
      sc2A = *qcA;                sc2B = *qcB;
      if (g4==0 && fl<12){
        sKA=loadKcol<KMODE>(qKA,fl); sKB=loadKcol<KMODE>(qKB,fl);
        if (t+1<TT-1){
          qFA += (size_t)BB*192; qFB += (size_t)BB*192;
          qfA2 += (size_t)BB*12; qfB2 += (size_t)BB*12;
          const float4* p4A=(const float4*)qFA; const float4* p4B=(const float4*)qFB;
          sFA0=p4A[0];sFA1=p4A[1];sFA2=p4A[2];sFA3=p4A[3];
          sFB0=p4B[0];sFB1=p4B[1];sFB2=p4B[2];sFB3=p4B[3];
          sfA_=*qfA2; sfB_=*qfB2;
        }
      }
      if (g4==0 && fl>=12){ skA_=loadkk<KMODE>(qKA,fl-12); skB_=loadkk<KMODE>(qKB,fl-12); }
    }

    float pA0=0.f,pA1=0.f,pA2=0.f,pA3=0.f, pB0=0.f,pB1=0.f,pB2=0.f,pB3=0.f;
    if (g4==0 && fl<12){
      pA0=KA4.x*xjA; pA1=KA4.y*xjA; pA2=KA4.z*xjA; pA3=KA4.w*xjA;
      pB0=KB4.x*xjB; pB1=KB4.y*xjB; pB2=KB4.z*xjB; pB3=KB4.w*xjB;
    }
    pA0=reduce16_dpp(pA0); pA1=reduce16_dpp(pA1);
    pA2=reduce16_dpp(pA2); pA3=reduce16_dpp(pA3);
    pB0=reduce16_dpp(pB0); pB1=reduce16_dpp(pB1);
    pB2=reduce16_dpp(pB2); pB3=reduce16_dpp(pB3);

    float* tbufA = tbA + (t&1)*16;
    float* tbufB = tbB + (t&1)*16;
    float tauA=0.f, tauB=0.f;
    if (g4==0){
      if (fl<12){ tauA=xjA; tauB=xjB; }
      else {
        const float uA=(fl==12)?pA0:(fl==13)?pA1:(fl==14)?pA2:pA3;
        const float uB=(fl==12)?pB0:(fl==13)?pB1:(fl==14)?pB2:pB3;
        tauA=uA+klA; tauB=uB+klB;
      }
      tbufA[fl]=tauA; tbufB[fl]=tauB;
    }
    FENCE();

    const float taulA = tbufA[fl];
    const float taulB = tbufB[fl];
    const float4 tqA = ((const float4*)tbufA)[g4];
    const float4 tqB = ((const float4*)tbufB)[g4];

    const float dotA = CaA.x*tqA.x + CaA.y*tqA.y + CaA.z*tqA.z + CaA.w*tqA.w;
    const float dotB = CaB.x*tqB.x + CaB.y*tqB.y + CaB.z*tqB.z + CaB.w*tqB.w;
    costA += (double)( taulA*0.5f*dotA + (g4==0 ? taulA*rcA : 0.f) );
    costB += (double)( taulB*0.5f*dotB + (g4==0 ? taulB*rcB : 0.f) );

    if (g4==0){
      if (fl<12){
        out[(size_t)t*BB*12 + (size_t)bA*12 + fl] = xjA;
        out[(size_t)t*BB*12 + (size_t)bB*12 + fl] = xjB;
      } else {
        out[(size_t)TT*BB*12 + (size_t)t*BB*4 + (size_t)bA*4 + (fl-12)] = tauA;
        out[(size_t)TT*BB*12 + (size_t)t*BB*4 + (size_t)bB*4 + (fl-12)] = tauB;
      }
    }

    if (t<TT-1 && g4==0 && fl<12){
      const float4* tpA=(const float4*)tbufA;
      const float4* tpB=(const float4*)tbufB;
      const float4 a0=tpA[0],a1=tpA[1],a2=tpA[2],a3=tpA[3];
      const float4 b0=tpB[0],b1=tpB[1],b2=tpB[2],b3=tpB[3];
      xjA = rfA
        + FA0.x*a0.x+FA0.y*a0.y+FA0.z*a0.z+FA0.w*a0.w
        + FA1.x*a1.x+FA1.y*a1.y+FA1.z*a1.z+FA1.w*a1.w
        + FA2.x*a2.x+FA2.y*a2.y+FA2.z*a2.z+FA2.w*a2.w
        + FA3.x*a3.x+FA3.y*a3.y+FA3.z*a3.z+FA3.w*a3.w;
      xjB = rfB
        + FB0.x*b0.x+FB0.y*b0.y+FB0.z*b0.z+FB0.w*b0.w
        + FB1.x*b1.x+FB1.y*b1.y+FB1.z*b1.z+FB1.w*b1.w
        + FB2.x*b2.x+FB2.y*b2.y+FB2.z*b2.z+FB2.w*b2.w
        + FB3.x*b3.x+FB3.y*b3.y+FB3.z*b3.z+FB3.w*b3.w;
    }
  }

  costA+=__shfl_xor(costA,1,64);  costA+=__shfl_xor(costA,2,64);
  costA+=__shfl_xor(costA,4,64);  costA+=__shfl_xor(costA,8,64);
  costA+=__shfl_xor(costA,16,64); costA+=__shfl_xor(costA,32,64);
  costB+=__shfl_xor(costB,1,64);  costB+=__shfl_xor(costB,2,64);
  costB+=__shfl_xor(costB,4,64);  costB+=__shfl_xor(costB,8,64);
  costB+=__shfl_xor(costB,16,64); costB+=__shfl_xor(costB,32,64);
  if (lane==0){
    out[(size_t)TT*BB*16 + bA]=(float)costA;
    out[(size_t)TT*BB*16 + bB]=(float)costB;
  }
}

extern "C" void kernel_launch(void* const* d_in, const int* in_sizes, int n_in,
                              void* d_out, int out_size, void* d_ws, size_t ws_size,
                              hipStream_t stream){
  (void)in_sizes; (void)n_in; (void)out_size;
  const float* xinit=(const float*)d_in[0];
  const float* C    =(const float*)d_in[1];
  const float* c    =(const float*)d_in[2];
  const float* F    =(const float*)d_in[3];
  const float* f    =(const float*)d_in[4];
  const size_t need_f32 = (size_t)TT*BB*52*sizeof(float);   // 85.2 MB
  if (ws_size >= need_f32){
    lqr_fused<0><<<dim3(BB/2), dim3(64), 0, stream>>>(xinit,C,c,F,f,(float*)d_out,d_ws);
  } else {
    lqr_fused<1><<<dim3(BB/2), dim3(64), 0, stream>>>(xinit,C,c,F,f,(float*)d_out,d_ws);
  }
}

// Round 18
// 422.449 us; speedup vs baseline: 1.2045x; 1.2045x over previous
//
#include <hip/hip_runtime.h>
#include <hip/hip_fp16.h>

#define TT 100
#define BB 4096
#define GS 488   // floats per batch blob (one batch per block)

// FINAL (R18 = R16, the session's measured optimum: 422.6 us).
//
// per-batch float layout:
//   V   [0,144)    12x12 value matrix, stored transposed (V[l*12+i]=Vn[i][l]);
//                  read as rows via symmetry (proven R11-R16)
//   Fl  [144,384)  12 rows x stride 20
//   vv  [384,396)  v
//   tb  [396,428)  ft (backward) / 2x16 tau ping-pong (forward)
//
// Lane layout: batch = ONE 64-lane wave. lane = 4*l + qd.
//   l = lane>>2 (column), qd = lane&3 (owns Q rows [4qd,4qd+4) of column l).
// Session findings baked in: row-partitioned Q (R14), v_rcp for all divisions
// + walking pointers (R15), 64-thread blocks (R16), DPP quad/row reductions
// (R12-R13), readlane Quu, single lgkm fence per backward step. R17's
// dual-batch ILP variant regressed (VGPR 2x -> occupancy cap halved).

#define FENCE() asm volatile("s_waitcnt lgkmcnt(0)" ::: "memory")

__device__ __forceinline__ float frcp(float x){ return __builtin_amdgcn_rcpf(x); }

template<int CTRL>
__device__ __forceinline__ float qbcast(float x){
  return __int_as_float(__builtin_amdgcn_update_dpp(0, __float_as_int(x), CTRL, 0xF, 0xF, true));
}
__device__ __forceinline__ float quadsum(float x){
  int a = __builtin_amdgcn_update_dpp(0, __float_as_int(x), 0xB1, 0xF, 0xF, true);
  x += __int_as_float(a);
  int c = __builtin_amdgcn_update_dpp(0, __float_as_int(x), 0x4E, 0xF, 0xF, true);
  x += __int_as_float(c);
  return x;
}
__device__ __forceinline__ float readlanef(float x, int srclane){
  return __int_as_float(__builtin_amdgcn_readlane(__float_as_int(x), srclane));
}
template<int CTRL>
__device__ __forceinline__ float ror_add(float x){
  int r = __builtin_amdgcn_update_dpp(0, __float_as_int(x), CTRL, 0xF, 0xF, true);
  return x + __int_as_float(r);
}
__device__ __forceinline__ float reduce16_dpp(float x){
  x = ror_add<0x128>(x); x = ror_add<0x124>(x);
  x = ror_add<0x122>(x); x = ror_add<0x121>(x);
  return x;
}

template<int KMODE>
__device__ __forceinline__ void storeK(void* wsb_, int l, float X0,float X1,float X2,float X3){
  if (KMODE==0){
    float* wsb=(float*)wsb_;
    if (l<12)       ((float4*)wsb)[l]  = make_float4(X0,X1,X2,X3);
    else if (l==12) ((float4*)wsb)[12] = make_float4(X0,X1,X2,X3);
  } else {
    __half* wsb=(__half*)wsb_;
    if (l<12){
      wsb[l*4+0]=__float2half(X0); wsb[l*4+1]=__float2half(X1);
      wsb[l*4+2]=__float2half(X2); wsb[l*4+3]=__float2half(X3);
    } else if (l==12){
      wsb[48]=__float2half(X0); wsb[49]=__float2half(X1);
      wsb[50]=__float2half(X2); wsb[51]=__float2half(X3);
    }
  }
}
template<int KMODE>
__device__ __forceinline__ float4 loadKcol(const void* wsb_, int l){
  if (KMODE==0) return ((const float4*)wsb_)[l];
  const __half* p=(const __half*)wsb_ + l*4;
  return make_float4(__half2float(p[0]),__half2float(p[1]),__half2float(p[2]),__half2float(p[3]));
}
template<int KMODE>
__device__ __forceinline__ float loadkk(const void* wsb_, int r){
  if (KMODE==0) return ((const float*)wsb_)[48+r];
  return __half2float(((const __half*)wsb_)[48+r]);
}

template<int KMODE>
__global__ __launch_bounds__(64)
void lqr_fused(const float* __restrict__ xinit,
               const float* __restrict__ Cg,
               const float* __restrict__ cg,
               const float* __restrict__ Fg,
               const float* __restrict__ fg,
               float* __restrict__ out,
               void* __restrict__ wsv)
{
  __shared__ float smem[GS];
  const int lane = threadIdx.x & 63;
  const int b    = blockIdx.x;
  const int l    = lane >> 2;
  const int qd   = lane & 3;

  float* __restrict__ Vb = smem;
  float* __restrict__ Fl = Vb + 144;
  float* __restrict__ vv = Vb + 384;
  float* __restrict__ tb = Vb + 396;

  if (l<12){
    if (qd<3) *(float4*)(Vb + l*12 + 4*qd) = make_float4(0,0,0,0);
    else vv[l]=0.f;
  }

  // ================= backward Riccati =================
  const size_t of0 = ((size_t)(TT-1)*BB + b);
  const float* pC = Cg + of0*256 + l*16 + 4*qd;
  const float* pc = cg + of0*16 + l;
  const float* pF = Fg + of0*192 + lane*4;
  const float* pf = fg + of0*12 + l;
  char*        pW = (char*)wsv + of0*52*(KMODE==0?4:2);

  float4 sCq; float sc_;
  float4 sFst=make_float4(0,0,0,0); float sftv=0.f;
  sCq = *(const float4*)pC;
  sc_ = *pc;

  for (int tt=TT-1; tt>=0; --tt){
    const bool hasF = (tt < TT-1);
    const float4 Cq=sCq; const float rc=sc_;
    const float4 Fst=sFst; const float ftv=sftv;

    if (hasF){
      if (lane<48) *(float4*)(Fl + l*20 + 4*qd) = Fst;
      if (qd==0 && l<12) tb[l]=ftv;
    }
    FENCE(); // the only backward fence

    if (tt>0){
      pC -= (size_t)BB*256; pc -= (size_t)BB*16;
      sCq = *(const float4*)pC;
      sc_ = *pc;
      if (lane<48){ pF -= (size_t)BB*192; sFst = *(const float4*)pF; }
      if (qd==0 && l<12){ pf -= (size_t)BB*12; sftv = *pf; }
    }

    float Qr0=Cq.x, Qr1=Cq.y, Qr2=Cq.z, Qr3=Cq.w;
    float qf=0.f;
    if (hasF){
      float Ftj[12];
      #pragma unroll
      for (int t=0;t<12;t++) Ftj[t]=Fl[t*20+l];
      const int s0=3*qd;
      float W0,W1,W2;
      {
        const float4* vr0=(const float4*)(Vb+(s0+0)*12);
        const float4* vr1=(const float4*)(Vb+(s0+1)*12);
        const float4* vr2=(const float4*)(Vb+(s0+2)*12);
        float4 a0=vr0[0],a1=vr0[1],a2=vr0[2];
        W0 = a0.x*Ftj[0]+a0.y*Ftj[1]+a0.z*Ftj[2]+a0.w*Ftj[3]
           + a1.x*Ftj[4]+a1.y*Ftj[5]+a1.z*Ftj[6]+a1.w*Ftj[7]
           + a2.x*Ftj[8]+a2.y*Ftj[9]+a2.z*Ftj[10]+a2.w*Ftj[11];
        float4 b0v=vr1[0],b1v=vr1[1],b2v=vr1[2];
        W1 = b0v.x*Ftj[0]+b0v.y*Ftj[1]+b0v.z*Ftj[2]+b0v.w*Ftj[3]
           + b1v.x*Ftj[4]+b1v.y*Ftj[5]+b1v.z*Ftj[6]+b1v.w*Ftj[7]
           + b2v.x*Ftj[8]+b2v.y*Ftj[9]+b2v.z*Ftj[10]+b2v.w*Ftj[11];
        float4 c0v=vr2[0],c1v=vr2[1],c2v=vr2[2];
        W2 = c0v.x*Ftj[0]+c0v.y*Ftj[1]+c0v.z*Ftj[2]+c0v.w*Ftj[3]
           + c1v.x*Ftj[4]+c1v.y*Ftj[5]+c1v.z*Ftj[6]+c1v.w*Ftj[7]
           + c2v.x*Ftj[8]+c2v.y*Ftj[9]+c2v.z*Ftj[10]+c2v.w*Ftj[11];
      }
      float Wf[12];
      Wf[0] =qbcast<0x00>(W0); Wf[1] =qbcast<0x00>(W1); Wf[2] =qbcast<0x00>(W2);
      Wf[3] =qbcast<0x55>(W0); Wf[4] =qbcast<0x55>(W1); Wf[5] =qbcast<0x55>(W2);
      Wf[6] =qbcast<0xAA>(W0); Wf[7] =qbcast<0xAA>(W1); Wf[8] =qbcast<0xAA>(W2);
      Wf[9] =qbcast<0xFF>(W0); Wf[10]=qbcast<0xFF>(W1); Wf[11]=qbcast<0xFF>(W2);
      #pragma unroll
      for (int s=0;s<12;s++){
        const float4 f4 = *(const float4*)(Fl + s*20 + 4*qd);
        Qr0 += f4.x*Wf[s]; Qr1 += f4.y*Wf[s];
        Qr2 += f4.z*Wf[s]; Qr3 += f4.w*Wf[s];
      }
      qf = W0*tb[s0] + W1*tb[s0+1] + W2*tb[s0+2];
      const float fta = qd==0?Ftj[0]:qd==1?Ftj[3]:qd==2?Ftj[6]:Ftj[9];
      const float ftb = qd==0?Ftj[1]:qd==1?Ftj[4]:qd==2?Ftj[7]:Ftj[10];
      const float ftc = qd==0?Ftj[2]:qd==1?Ftj[5]:qd==2?Ftj[8]:Ftj[11];
      qf += fta*vv[s0] + ftb*vv[s0+1] + ftc*vv[s0+2];
    }
    const float qv = rc + quadsum(qf);

    float a00=readlanef(Qr0,51),a01=readlanef(Qr0,55),a02=readlanef(Qr0,59),a03=readlanef(Qr0,63);
    float a10=readlanef(Qr1,51),a11=readlanef(Qr1,55),a12=readlanef(Qr1,59),a13=readlanef(Qr1,63);
    float a20=readlanef(Qr2,51),a21=readlanef(Qr2,55),a22=readlanef(Qr2,59),a23=readlanef(Qr2,63);
    float a30=readlanef(Qr3,51),a31=readlanef(Qr3,55),a32=readlanef(Qr3,59),a33=readlanef(Qr3,63);
    const float qu0=readlanef(qv,48),qu1=readlanef(qv,52),qu2=readlanef(qv,56),qu3=readlanef(qv,60);

    const float b0=-qbcast<0xFF>(Qr0), b1=-qbcast<0xFF>(Qr1),
                b2=-qbcast<0xFF>(Qr2), b3=-qbcast<0xFF>(Qr3);
    float bb0=b0,bb1=b1,bb2=b2,bb3=b3;

    const float i0=frcp(a00);
    const float m10=a10*i0,m20=a20*i0,m30=a30*i0;
    a11-=m10*a01;a12-=m10*a02;a13-=m10*a03;
    a21-=m20*a01;a22-=m20*a02;a23-=m20*a03;
    a31-=m30*a01;a32-=m30*a02;a33-=m30*a03;
    bb1-=m10*bb0;bb2-=m20*bb0;bb3-=m30*bb0;
    const float i1=frcp(a11);
    const float m21=a21*i1,m31=a31*i1;
    a22-=m21*a12;a23-=m21*a13;
    a32-=m31*a12;a33-=m31*a13;
    bb2-=m21*bb1;bb3-=m31*bb1;
    const float i2=frcp(a22);
    const float m32=a32*i2;
    a33-=m32*a23;
    bb3-=m32*bb2;
    const float i3=frcp(a33);
    const float X3=bb3*i3;
    const float X2=(bb2-a23*X3)*i2;
    const float X1=(bb1-a12*X2-a13*X3)*i1;
    const float X0=(bb0-a01*X1-a02*X2-a03*X3)*i0;
    float c0=-qu0,c1=-qu1,c2=-qu2,c3=-qu3;
    c1-=m10*c0;c2-=m20*c0;c3-=m30*c0;
    c2-=m21*c1;c3-=m31*c1;
    c3-=m32*c2;
    const float k3=c3*i3;
    const float k2v=(c2-a23*k3)*i2;
    const float k1=(c1-a12*k2v-a13*k3)*i1;
    const float k0=(c0-a01*k1-a02*k2v-a03*k3)*i0;

    if (qd==0)
      storeK<KMODE>(pW, l, l<12?X0:k0, l<12?X1:k1, l<12?X2:k2v, l<12?X3:k3);
    pW -= (size_t)BB*52*(KMODE==0?4:2);

    float vn0=Qr0, vn1=Qr1, vn2=Qr2, vn3=Qr3;
    #pragma unroll
    for (int r=0;r<4;r++){
      const float Xr = r==0?X0:r==1?X1:r==2?X2:X3;
      vn0 += __shfl(Qr0, 48+4*r+qd, 64) * Xr;
      vn1 += __shfl(Qr1, 48+4*r+qd, 64) * Xr;
      vn2 += __shfl(Qr2, 48+4*r+qd, 64) * Xr;
      vn3 += __shfl(Qr3, 48+4*r+qd, 64) * Xr;
    }
    if (l<12){
      if (qd<3){
        *(float4*)(Vb + l*12 + 4*qd) = make_float4(vn0,vn1,vn2,vn3);
      } else {
        vv[l] = qv + Qr0*k0 + Qr1*k1 + Qr2*k2v + Qr3*k3;
      }
    }
  }

  // drain K/k global stores before forward reads them
  asm volatile("s_waitcnt vmcnt(0)" ::: "memory");

  // ================= forward rollout =================
  const int fl = lane & 15;
  const int g4 = lane >> 4;

  float xj = (g4==0 && fl<12)? xinit[(size_t)b*12+fl] : 0.f;
  double costacc=0.0;

  const float* qC = Cg + (size_t)b*256 + fl*16 + 4*g4;
  const float* qc = cg + (size_t)b*16 + fl;
  const float* qF = Fg + (size_t)b*192 + fl*16;
  const float* qf2= fg + (size_t)b*12 + fl;
  const char*  qK = (const char*)wsv + (size_t)b*52*(KMODE==0?4:2);

  float4 sCa; float sc2_;
  float4 sF0=make_float4(0,0,0,0),sF1=sF0,sF2=sF0,sF3=sF0; float sf_=0.f;
  float4 sK=make_float4(0,0,0,0); float sk_=0.f;
  {
    sCa = *(const float4*)qC;
    sc2_= *qc;
    if (g4==0 && fl<12){
      const float4* pf4=(const float4*)qF;
      sF0=pf4[0];sF1=pf4[1];sF2=pf4[2];sF3=pf4[3];
      sf_=*qf2;
      sK=loadKcol<KMODE>(qK,fl);
    }
    if (g4==0 && fl>=12) sk_=loadkk<KMODE>(qK,fl-12);
  }

  for (int t=0;t<TT;t++){
    float4 Ca=sCa; float rc=sc2_;
    float4 F0=sF0,F1=sF1,F2=sF2,F3=sF3; float rf=sf_;
    float4 K4=sK; float kl=sk_;

    if (t+1<TT){
      qC += (size_t)BB*256; qc += (size_t)BB*16; qK += (size_t)BB*52*(KMODE==0?4:2);
      sCa = *(const float4*)qC;
      sc2_= *qc;
      if (g4==0 && fl<12){
        sK=loadKcol<KMODE>(qK,fl);
        if (t+1<TT-1){
          qF += (size_t)BB*192; qf2 += (size_t)BB*12;
          const float4* pf4=(const float4*)qF;
          sF0=pf4[0];sF1=pf4[1];sF2=pf4[2];sF3=pf4[3];
          sf_=*qf2;
        }
      }
      if (g4==0 && fl>=12) sk_=loadkk<KMODE>(qK,fl-12);
    }

    float pr0=0.f,pr1=0.f,pr2=0.f,pr3=0.f;
    if (g4==0 && fl<12){ pr0=K4.x*xj; pr1=K4.y*xj; pr2=K4.z*xj; pr3=K4.w*xj; }
    pr0=reduce16_dpp(pr0); pr1=reduce16_dpp(pr1);
    pr2=reduce16_dpp(pr2); pr3=reduce16_dpp(pr3);

    float* tbuf = tb + (t&1)*16;
    float tauj=0.f;
    if (g4==0){
      if (fl<12) tauj=xj;
      else {
        const float ur=(fl==12)?pr0:(fl==13)?pr1:(fl==14)?pr2:pr3;
        tauj=ur+kl;
      }
      tbuf[fl]=tauj;
    }
    FENCE();

    const float taul = tbuf[fl];
    const float4 tq = ((const float4*)tbuf)[g4];

    const float dot_p = Ca.x*tq.x + Ca.y*tq.y + Ca.z*tq.z + Ca.w*tq.w;
    costacc += (double)( taul*0.5f*dot_p + (g4==0 ? taul*rc : 0.f) );

    if (g4==0){
      if (fl<12) out[(size_t)t*BB*12 + (size_t)b*12 + fl] = xj;
      else       out[(size_t)TT*BB*12 + (size_t)t*BB*4 + (size_t)b*4 + (fl-12)] = tauj;
    }

    if (t<TT-1 && g4==0 && fl<12){
      const float4* tp=(const float4*)tbuf;
      const float4 t0=tp[0],t1=tp[1],t2=tp[2],t3=tp[3];
      xj = rf
         + F0.x*t0.x+F0.y*t0.y+F0.z*t0.z+F0.w*t0.w
         + F1.x*t1.x+F1.y*t1.y+F1.z*t1.z+F1.w*t1.w
         + F2.x*t2.x+F2.y*t2.y+F2.z*t2.z+F2.w*t2.w
         + F3.x*t3.x+F3.y*t3.y+F3.z*t3.z+F3.w*t3.w;
    }
  }

  costacc+=__shfl_xor(costacc,1,64);  costacc+=__shfl_xor(costacc,2,64);
  costacc+=__shfl_xor(costacc,4,64);  costacc+=__shfl_xor(costacc,8,64);
  costacc+=__shfl_xor(costacc,16,64); costacc+=__shfl_xor(costacc,32,64);
  if (lane==0) out[(size_t)TT*BB*16 + b]=(float)costacc;
}

extern "C" void kernel_launch(void* const* d_in, const int* in_sizes, int n_in,
                              void* d_out, int out_size, void* d_ws, size_t ws_size,
                              hipStream_t stream){
  (void)in_sizes; (void)n_in; (void)out_size;
  const float* xinit=(const float*)d_in[0];
  const float* C    =(const float*)d_in[1];
  const float* c    =(const float*)d_in[2];
  const float* F    =(const float*)d_in[3];
  const float* f    =(const float*)d_in[4];
  const size_t need_f32 = (size_t)TT*BB*52*sizeof(float);   // 85.2 MB
  if (ws_size >= need_f32){
    lqr_fused<0><<<dim3(BB), dim3(64), 0, stream>>>(xinit,C,c,F,f,(float*)d_out,d_ws);
  } else {
    lqr_fused<1><<<dim3(BB), dim3(64), 0, stream>>>(xinit,C,c,F,f,(float*)d_out,d_ws);
  }
}